// Round 1
// baseline (165.864 us; speedup 1.0000x reference)
//
#include <hip/hip_runtime.h>
#include <math.h>

// Problem constants (B=4, Nin=64, F=64, T=1024, NH=8, FDIM=64, N=512)
#define QSCALE 0.18033688011112042f   // 0.125 * log2(e): softmax scale folded, exp2 domain

typedef __attribute__((ext_vector_type(4))) float  f32x4;
typedef __attribute__((ext_vector_type(2))) float  f32x2;
typedef __attribute__((ext_vector_type(8))) short  bf16x8;   // MFMA A/B frag (8 bf16)
typedef __attribute__((ext_vector_type(4))) short  bf16x4;   // 8B packed store
typedef __attribute__((ext_vector_type(4))) int    i32x4;    // 16B copy

static __device__ __forceinline__ short f2bf(float f) {
    union { float f; unsigned u; } v; v.f = f;
    unsigned r = v.u + 0x7fffu + ((v.u >> 16) & 1u);   // RNE
    return (short)(r >> 16);
}
static __device__ __forceinline__ int pk2bf(float a, float b) {
    return ((int)f2bf(a) & 0xffff) | ((int)f2bf(b) << 16);
}

#define MFMA16(A,B,C) __builtin_amdgcn_mfma_f32_16x16x32_bf16(A, B, C, 0, 0, 0)

// ---------------------------------------------------------------------------
// Kernel 1: xi[b,h,f,t] = sum_c w_in[h,c] * x[b,c,f,t]
// 2 t per thread (131072 threads = 8 waves/CU), f32x2 loads, depth-8 pipeline.
// Outputs: xi_v[b][h][f][t] bf16; xr_t[b][t][c] bf16 via LDS transpose.
// Grid (16 tb, 8 fb, 4 b) = 512 blocks.
// ---------------------------------------------------------------------------
__global__ __launch_bounds__(256) void k_proj_in(
    const float* __restrict__ x, const float* __restrict__ w_in,
    short* __restrict__ xi_v, short* __restrict__ xr_t)
{
    __shared__ float w_s[512];                    // w_in [8][64]
    __shared__ __align__(16) short tr[64 * 72];   // [t-local][c'=h*8+fy], pad 72
    int tid = threadIdx.x;
    int tx = tid & 31, fy = tid >> 5;
    int tb = blockIdx.x, fb = blockIdx.y, b = blockIdx.z;
    w_s[tid] = w_in[tid & 511];
    w_s[(tid + 256) & 511] = w_in[(tid + 256) & 511];
    __syncthreads();

    int f = fb * 8 + fy;
    int t = tb * 64 + tx * 2;
    float acc[8][2];
    #pragma unroll
    for (int h = 0; h < 8; h++) { acc[h][0] = 0.f; acc[h][1] = 0.f; }

    const float* xp = x + ((size_t)b * 64 * 64 + (size_t)f) * 1024 + t;
    f32x2 buf[8];
    #pragma unroll
    for (int i = 0; i < 8; i++) buf[i] = *(const f32x2*)&xp[(size_t)i * 65536];
    #pragma unroll
    for (int c8 = 0; c8 < 64; c8 += 8) {
        f32x2 cur[8];
        #pragma unroll
        for (int i = 0; i < 8; i++) cur[i] = buf[i];
        if (c8 + 8 < 64) {
            #pragma unroll
            for (int i = 0; i < 8; i++)
                buf[i] = *(const f32x2*)&xp[(size_t)(c8 + 8 + i) * 65536];
        }
        #pragma unroll
        for (int i = 0; i < 8; i++)
            #pragma unroll
            for (int h = 0; h < 8; h++) {
                float wv = w_s[h * 64 + c8 + i];
                acc[h][0] = fmaf(cur[i][0], wv, acc[h][0]);
                acc[h][1] = fmaf(cur[i][1], wv, acc[h][1]);
            }
    }
    // xi_v[b][h][f][t..t+1] (4B packed store)
    #pragma unroll
    for (int h = 0; h < 8; h++)
        *(int*)&xi_v[(((size_t)b * 8 + h) * 64 + f) * 1024 + t] = pk2bf(acc[h][0], acc[h][1]);
    // transpose to xr_t via LDS
    #pragma unroll
    for (int h = 0; h < 8; h++) {
        tr[(tx * 2 + 0) * 72 + h * 8 + fy] = f2bf(acc[h][0]);
        tr[(tx * 2 + 1) * 72 + h * 8 + fy] = f2bf(acc[h][1]);
    }
    __syncthreads();
    int h2 = tid & 7, trow = tid >> 3;            // trow 0..31
    #pragma unroll
    for (int i = 0; i < 2; i++) {
        int t2 = trow + i * 32;
        i32x4 v = *(const i32x4*)&tr[t2 * 72 + h2 * 8];
        *(i32x4*)&xr_t[((size_t)b * 1024 + tb * 64 + t2) * 512 + h2 * 64 + fb * 8] = v;
    }
}

// ---------------------------------------------------------------------------
// Kernel 2: qk[D][t] = sum_c w_qk[D][c] * xr[c][t]   (per batch)
// fp32 w_qk converted+scaled inline during A-staging (k_prep fused away):
// the 64-row D-tile is entirely q (Dt even) or k (Dt odd), so scale is
// block-uniform. Tiles 64D x 64t, BK=64, grid (16 t, 16 D, 4 b) = 1024
// blocks, 18.4KB LDS -> 4 blocks/CU. Store qk_t[b][h][t][d2], d2 = D&127.
// ---------------------------------------------------------------------------
__global__ __launch_bounds__(256, 4) void k_qk(
    const float* __restrict__ wqk, const short* __restrict__ xr_t,
    short* __restrict__ qk_t)
{
    __shared__ __align__(16) short As[64 * 72];   // [D-local][64 data + 8 pad]
    __shared__ __align__(16) short Bs[64 * 72];   // [t-local][64 data + 8 pad]
    int tid = threadIdx.x;
    int w = tid >> 6, lane = tid & 63;
    int quad = lane >> 4, l16 = lane & 15;
    int t0 = blockIdx.x * 64;
    int Dt = blockIdx.y;                          // D0 = Dt*64; h = Dt>>1
    int b  = blockIdx.z;

    f32x4 acc[4];
    #pragma unroll
    for (int tt = 0; tt < 4; tt++) acc[tt] = (f32x4){0.f,0.f,0.f,0.f};

    int s_row = tid >> 2, s_col = (tid & 3) * 16;
    const float* Ag = wqk + ((size_t)Dt * 64 + s_row) * 512;
    const short* Bg = xr_t + ((size_t)b * 1024 + t0) * 512;
    float s = (Dt & 1) ? 1.0f : QSCALE;           // q rows get scale, k rows 1

    for (int kk = 0; kk < 512; kk += 64) {
        __syncthreads();
        f32x4 a0 = *(const f32x4*)&Ag[kk + s_col];
        f32x4 a1 = *(const f32x4*)&Ag[kk + s_col + 4];
        f32x4 a2 = *(const f32x4*)&Ag[kk + s_col + 8];
        f32x4 a3 = *(const f32x4*)&Ag[kk + s_col + 12];
        i32x4 w0, w1;
        w0[0] = pk2bf(a0[0]*s, a0[1]*s); w0[1] = pk2bf(a0[2]*s, a0[3]*s);
        w0[2] = pk2bf(a1[0]*s, a1[1]*s); w0[3] = pk2bf(a1[2]*s, a1[3]*s);
        w1[0] = pk2bf(a2[0]*s, a2[1]*s); w1[1] = pk2bf(a2[2]*s, a2[3]*s);
        w1[2] = pk2bf(a3[0]*s, a3[1]*s); w1[3] = pk2bf(a3[2]*s, a3[3]*s);
        *(i32x4*)&As[s_row * 72 + s_col]     = w0;
        *(i32x4*)&As[s_row * 72 + s_col + 8] = w1;
        *(i32x4*)&Bs[s_row * 72 + s_col] =
            *(const i32x4*)&Bg[(size_t)s_row * 512 + kk + s_col];
        *(i32x4*)&Bs[s_row * 72 + s_col + 8] =
            *(const i32x4*)&Bg[(size_t)s_row * 512 + kk + s_col + 8];
        __syncthreads();
        bf16x8 af[2];
        #pragma unroll
        for (int kc = 0; kc < 2; kc++)
            af[kc] = *(const bf16x8*)&As[(w * 16 + l16) * 72 + kc * 32 + quad * 8];
        #pragma unroll
        for (int tt = 0; tt < 4; tt++) {
            bf16x8 bf0 = *(const bf16x8*)&Bs[(tt * 16 + l16) * 72 + quad * 8];
            bf16x8 bf1 = *(const bf16x8*)&Bs[(tt * 16 + l16) * 72 + 32 + quad * 8];
            acc[tt] = MFMA16(af[0], bf0, acc[tt]);
            acc[tt] = MFMA16(af[1], bf1, acc[tt]);
        }
    }
    int h = Dt >> 1;
    int d2 = (Dt & 1) * 64 + w * 16 + quad * 4;
    #pragma unroll
    for (int tt = 0; tt < 4; tt++) {
        bf16x4 pk;
        pk.x = f2bf(acc[tt][0]); pk.y = f2bf(acc[tt][1]);
        pk.z = f2bf(acc[tt][2]); pk.w = f2bf(acc[tt][3]);
        int t = t0 + tt * 16 + l16;
        *(bf16x4*)&qk_t[(((size_t)b * 8 + h) * 1024 + t) * 128 + d2] = pk;
    }
}

// ---------------------------------------------------------------------------
// Kernel 3: attention, NO-MAX softmax, FULL m-range per block (mh split
// removed). 16 m-tiles of 64, register-double-buffered staging, in-kernel
// normalization (l redistributed via wave shuffles -> no extra LDS/barrier).
// Writes normalized fp32 o_n[bh][f][t] (8 MB; was 32.5 MB o_part+lsum RW).
// Grid 512 blocks (flattened, XCD-chunked swizzle: 4 bh-groups = 1 MB K/V
// working set per XCD L2), 36KB LDS -> 2 blocks/CU co-resident.
// ---------------------------------------------------------------------------
__global__ __launch_bounds__(256, 4) void k_attn(
    const short* __restrict__ qk_t, const short* __restrict__ xi_v,
    const float* __restrict__ rel_bias, float* __restrict__ o_n)
{
    __shared__ __align__(16) short Ks[64 * 72];       // [m][64 data + 8 pad]
    __shared__ __align__(16) short Vs[64 * 72];       // [d][64 m + 8 pad]
    __shared__ __align__(16) short Ps[4][16 * 72];    // per wave [n][64 + 8 pad]
    __shared__ float elut[2048];
    int tid = threadIdx.x;
    int w = tid >> 6, lane = tid & 63;
    int quad = lane >> 4, l16 = lane & 15;
    // XCD-chunked bijective swizzle (512 = 8 XCDs x 64): keeps the 16
    // nb-siblings of a bh (shared K/V stream) on one XCD's L2.
    int bid = blockIdx.x;
    int wg = (bid & 7) * 64 + (bid >> 3);
    int nb = wg & 15, bh = wg >> 4;
    int h = bh & 7;
    int n_base = nb * 64;

    for (int i = tid; i < 2047; i += 256) {
        int rel = i - 1023;
        int ret = (rel >= 0) ? 16 : 0;
        int na = rel < 0 ? -rel : rel;
        int idx;
        if (na < 8) idx = ret + na;
        else {
            int vl = 8 + (int)(log2f((float)na * 0.125f) * 2.0f);
            vl = vl > 15 ? 15 : vl;
            idx = ret + vl;
        }
        elut[i] = exp2f(rel_bias[idx * 8 + h] * QSCALE);
    }

    const short* qb = qk_t + (size_t)bh * (1024 * 128);
    const short* vb = xi_v + (size_t)bh * (64 * 1024);

    // Q frags (B-operand): lane holds Q[n = n_base + w*16 + l16][kk*32+quad*8+j]
    bf16x8 qf[2];
    #pragma unroll
    for (int kk = 0; kk < 2; kk++)
        qf[kk] = *(const bf16x8*)&qb[(size_t)(n_base + w * 16 + l16) * 128 + kk * 32 + quad * 8];

    f32x4 acc_o[4];
    #pragma unroll
    for (int dt = 0; dt < 4; dt++) acc_o[dt] = (f32x4){0.f,0.f,0.f,0.f};
    float l_st = 0.f;

    // staging map: 4 threads per row, 2 x 16B each
    int srow = tid >> 2;                // 0..63 (m-local for K, d for V)
    int soff = (tid & 3) * 16;          // 0,16,32,48
    int m0 = 0;
    i32x4 gk[2], gv[2];
    #pragma unroll
    for (int i = 0; i < 2; i++) {
        gk[i] = *(const i32x4*)&qb[(size_t)(m0 + srow) * 128 + 64 + soff + i * 8];
        gv[i] = *(const i32x4*)&vb[(size_t)srow * 1024 + m0 + soff + i * 8];
    }

    __syncthreads();   // elut ready

    #pragma unroll 1
    for (int it = 0; it < 16; it++) {
        *(i32x4*)&Ks[srow * 72 + soff]     = gk[0];
        *(i32x4*)&Ks[srow * 72 + soff + 8] = gk[1];
        *(i32x4*)&Vs[srow * 72 + soff]     = gv[0];
        *(i32x4*)&Vs[srow * 72 + soff + 8] = gv[1];
        __syncthreads();
        // prefetch next tile into registers (overlaps compute below)
        if (it < 15) {
            int m1 = m0 + 64;
            #pragma unroll
            for (int i = 0; i < 2; i++) {
                gk[i] = *(const i32x4*)&qb[(size_t)(m1 + srow) * 128 + 64 + soff + i * 8];
                gv[i] = *(const i32x4*)&vb[(size_t)srow * 1024 + m1 + soff + i * 8];
            }
        }

        // sim^T: A = K (m rows), B = Q (n cols); D[m][n], col n = l16
        f32x4 s[4];
        #pragma unroll
        for (int mt = 0; mt < 4; mt++) {
            bf16x8 kf0 = *(const bf16x8*)&Ks[(mt * 16 + l16) * 72 + quad * 8];
            bf16x8 kf1 = *(const bf16x8*)&Ks[(mt * 16 + l16) * 72 + 32 + quad * 8];
            f32x4 tacc = (f32x4){0.f,0.f,0.f,0.f};
            tacc = MFMA16(kf0, qf[0], tacc);
            tacc = MFMA16(kf1, qf[1], tacc);
            s[mt] = tacc;
        }

        // p = exp2(s) * elut[rel]; accumulate l (per-lane partial)
        int n = n_base + w * 16 + l16;
        #pragma unroll
        for (int mt = 0; mt < 4; mt++) {
            int rel0 = m0 + mt * 16 + quad * 4 - n + 1023;
            #pragma unroll
            for (int j = 0; j < 4; j++) {
                float p = exp2f(s[mt][j]) * elut[rel0 + j];
                s[mt][j] = p;
                l_st += p;
            }
        }
        // pack P into per-wave LDS (C-layout -> A-layout)
        #pragma unroll
        for (int mt = 0; mt < 4; mt++) {
            bf16x4 pk;
            pk.x = f2bf(s[mt][0]); pk.y = f2bf(s[mt][1]);
            pk.z = f2bf(s[mt][2]); pk.w = f2bf(s[mt][3]);
            *(bf16x4*)&Ps[w][l16 * 72 + mt * 16 + quad * 4] = pk;
        }
        // PV: O[n][d] += P[n][m] V[m][d]
        #pragma unroll
        for (int si = 0; si < 2; si++) {
            bf16x8 pf = *(const bf16x8*)&Ps[w][l16 * 72 + si * 32 + quad * 8];
            #pragma unroll
            for (int dt = 0; dt < 4; dt++) {
                bf16x8 vf = *(const bf16x8*)&Vs[(dt * 16 + l16) * 72 + si * 32 + quad * 8];
                acc_o[dt] = MFMA16(pf, vf, acc_o[dt]);
            }
        }
        m0 += 64;
        __syncthreads();
    }
    // full column sums: lane holds l for col n-local = w*16 + l16 after
    // cross-quad butterfly; redistribute to the store layout (col = quad*4+j)
    // via intra-wave shuffles (source lane quad*4+j holds that column).
    l_st += __shfl_xor(l_st, 16);
    l_st += __shfl_xor(l_st, 32);
    float linv[4];
    #pragma unroll
    for (int j = 0; j < 4; j++)
        linv[j] = 1.0f / __shfl(l_st, quad * 4 + j);
    // store normalized O: o_n[bh][d][n], d = dt*16+l16, n = n_base+w*16+quad*4+j
    #pragma unroll
    for (int dt = 0; dt < 4; dt++) {
        f32x4 ov;
        #pragma unroll
        for (int j = 0; j < 4; j++) ov[j] = acc_o[dt][j] * linv[j];
        *(f32x4*)&o_n[(((size_t)bh) * 64 + dt * 16 + l16) * 1024 + n_base + w * 16 + quad * 4] = ov;
    }
}

// ---------------------------------------------------------------------------
// Kernel 4: output projection only (merge/normalize moved into k_attn)
// out[b,c,f,t] = sum_h o_n[b,h,f,t] w_out[c,h]
// ---------------------------------------------------------------------------
__global__ __launch_bounds__(512) void k_proj_out(
    const float* __restrict__ o_n, const float* __restrict__ w_out,
    float* __restrict__ out)
{
    __shared__ float w_s[512];
    __shared__ float o_s[8][64];
    int tid = threadIdx.x;
    int tx = tid & 63, ty = tid >> 6;
    int tb = blockIdx.x, f = blockIdx.y, b = blockIdx.z;
    w_s[tid] = w_out[tid];
    int t = tb * 64 + tx;
    o_s[ty][tx] = o_n[((size_t)(b * 8 + ty) * 64 + f) * 1024 + t];
    __syncthreads();
    float ov[8];
    #pragma unroll
    for (int hh = 0; hh < 8; hh++) ov[hh] = o_s[hh][tx];
    #pragma unroll
    for (int j = 0; j < 8; j++) {
        int c = ty * 8 + j;
        float a = 0.f;
        #pragma unroll
        for (int hh = 0; hh < 8; hh++) a = fmaf(ov[hh], w_s[c * 8 + hh], a);
        out[(((size_t)b * 64 + c) * 64 + f) * 1024 + t] = a;
    }
}

// ---------------------------------------------------------------------------
extern "C" void kernel_launch(void* const* d_in, const int* in_sizes, int n_in,
                              void* d_out, int out_size, void* d_ws, size_t ws_size,
                              hipStream_t stream)
{
    const float* x        = (const float*)d_in[0];   // [4][64][64][1024]
    const float* w_in     = (const float*)d_in[1];   // [8][64]
    const float* w_qk     = (const float*)d_in[2];   // [1024][512]
    const float* w_out    = (const float*)d_in[3];   // [64][8]
    const float* rel_bias = (const float*)d_in[4];   // [32][8]
    float* out = (float*)d_out;                      // [4][64][64][1024]

    char* ws = (char*)d_ws;                          // 24 MB used
    short* xi_v = (short*)(ws);                      // 4 MB
    short* xr_t = (short*)(ws + (size_t)4  * (1 << 20));  // 4 MB
    short* qk_t = (short*)(ws + (size_t)8  * (1 << 20));  // 8 MB
    float* o_n  = (float*)(ws + (size_t)16 * (1 << 20));  // 8 MB

    hipLaunchKernelGGL(k_proj_in,  dim3(16, 8, 4),   dim3(256), 0, stream, x, w_in, xi_v, xr_t);
    hipLaunchKernelGGL(k_qk,       dim3(16, 16, 4),  dim3(256), 0, stream, w_qk, xr_t, qk_t);
    hipLaunchKernelGGL(k_attn,     dim3(512),        dim3(256), 0, stream, qk_t, xi_v, rel_bias, o_n);
    hipLaunchKernelGGL(k_proj_out, dim3(16, 64, 4),  dim3(512), 0, stream, o_n, w_out, out);
}

// Round 2
// 160.807 us; speedup vs baseline: 1.0314x; 1.0314x over previous
//
#include <hip/hip_runtime.h>
#include <math.h>

// Problem constants (B=4, Nin=64, F=64, T=1024, NH=8, FDIM=64, N=512)
#define QSCALE 0.18033688011112042f   // 0.125 * log2(e): softmax scale folded, exp2 domain

typedef __attribute__((ext_vector_type(4))) float  f32x4;
typedef __attribute__((ext_vector_type(2))) float  f32x2;
typedef __attribute__((ext_vector_type(8))) short  bf16x8;   // MFMA A/B frag (8 bf16)
typedef __attribute__((ext_vector_type(4))) short  bf16x4;   // 8B packed store
typedef __attribute__((ext_vector_type(4))) int    i32x4;    // 16B copy

static __device__ __forceinline__ short f2bf(float f) {
    union { float f; unsigned u; } v; v.f = f;
    unsigned r = v.u + 0x7fffu + ((v.u >> 16) & 1u);   // RNE
    return (short)(r >> 16);
}
static __device__ __forceinline__ int pk2bf(float a, float b) {
    return ((int)f2bf(a) & 0xffff) | ((int)f2bf(b) << 16);
}

#define MFMA16(A,B,C) __builtin_amdgcn_mfma_f32_16x16x32_bf16(A, B, C, 0, 0, 0)

// ---------------------------------------------------------------------------
// Kernel 1: xi[b,h,f,t] = sum_c w_in[h,c] * x[b,c,f,t]
// 2 t per thread (131072 threads = 8 waves/CU), f32x2 loads, depth-8 pipeline.
// Outputs: xi_v[b][h][f][t] bf16; xr_t[b][t][c] bf16 via LDS transpose.
// Also performs the one-shot w_qk fp32->bf16 conversion (4 elems/thread),
// scale folded into q rows -- replaces the separate k_prep launch.
// Grid (16 tb, 8 fb, 4 b) = 512 blocks.
// ---------------------------------------------------------------------------
__global__ __launch_bounds__(256) void k_proj_in(
    const float* __restrict__ x, const float* __restrict__ w_in,
    const float* __restrict__ wqk, short* __restrict__ wqk_b,
    short* __restrict__ xi_v, short* __restrict__ xr_t)
{
    __shared__ float w_s[512];                    // w_in [8][64]
    __shared__ __align__(16) short tr[64 * 72];   // [t-local][c'=h*8+fy], pad 72
    int tid = threadIdx.x;
    int tx = tid & 31, fy = tid >> 5;
    int tb = blockIdx.x, fb = blockIdx.y, b = blockIdx.z;

    // fused w_qk conversion: 512 blocks x 256 thr x 4 elems = 524288 (exact)
    {
        int gi = (((b * 8 + fb) * 16 + tb) * 256 + tid) * 4;
        f32x4 wv = *(const f32x4*)&wqk[gi];
        float s = ((gi >> 9) & 64) ? 1.0f : QSCALE;   // q rows scaled, k rows 1
        bf16x4 pk;
        pk.x = f2bf(wv[0] * s); pk.y = f2bf(wv[1] * s);
        pk.z = f2bf(wv[2] * s); pk.w = f2bf(wv[3] * s);
        *(bf16x4*)&wqk_b[gi] = pk;
    }

    w_s[tid] = w_in[tid & 511];
    w_s[(tid + 256) & 511] = w_in[(tid + 256) & 511];
    __syncthreads();

    int f = fb * 8 + fy;
    int t = tb * 64 + tx * 2;
    float acc[8][2];
    #pragma unroll
    for (int h = 0; h < 8; h++) { acc[h][0] = 0.f; acc[h][1] = 0.f; }

    const float* xp = x + ((size_t)b * 64 * 64 + (size_t)f) * 1024 + t;
    f32x2 buf[8];
    #pragma unroll
    for (int i = 0; i < 8; i++) buf[i] = *(const f32x2*)&xp[(size_t)i * 65536];
    #pragma unroll
    for (int c8 = 0; c8 < 64; c8 += 8) {
        f32x2 cur[8];
        #pragma unroll
        for (int i = 0; i < 8; i++) cur[i] = buf[i];
        if (c8 + 8 < 64) {
            #pragma unroll
            for (int i = 0; i < 8; i++)
                buf[i] = *(const f32x2*)&xp[(size_t)(c8 + 8 + i) * 65536];
        }
        #pragma unroll
        for (int i = 0; i < 8; i++)
            #pragma unroll
            for (int h = 0; h < 8; h++) {
                float wv = w_s[h * 64 + c8 + i];
                acc[h][0] = fmaf(cur[i][0], wv, acc[h][0]);
                acc[h][1] = fmaf(cur[i][1], wv, acc[h][1]);
            }
    }
    // xi_v[b][h][f][t..t+1] (4B packed store)
    #pragma unroll
    for (int h = 0; h < 8; h++)
        *(int*)&xi_v[(((size_t)b * 8 + h) * 64 + f) * 1024 + t] = pk2bf(acc[h][0], acc[h][1]);
    // transpose to xr_t via LDS
    #pragma unroll
    for (int h = 0; h < 8; h++) {
        tr[(tx * 2 + 0) * 72 + h * 8 + fy] = f2bf(acc[h][0]);
        tr[(tx * 2 + 1) * 72 + h * 8 + fy] = f2bf(acc[h][1]);
    }
    __syncthreads();
    int h2 = tid & 7, trow = tid >> 3;            // trow 0..31
    #pragma unroll
    for (int i = 0; i < 2; i++) {
        int t2 = trow + i * 32;
        i32x4 v = *(const i32x4*)&tr[t2 * 72 + h2 * 8];
        *(i32x4*)&xr_t[((size_t)b * 1024 + tb * 64 + t2) * 512 + h2 * 64 + fb * 8] = v;
    }
}

// ---------------------------------------------------------------------------
// Kernel 2: qk[D][t] = sum_c wqk_b[D][c] * xr[c][t]   (per batch)
// Tiles 64D x 64t, BK=64, 1024 blocks 1D with XCD-chunked swizzle (each XCD
// gets 8 (tb,b) groups x all 16 Dt -> A fully L2-resident, B 512KB/XCD).
// Register double-buffered staging (stage-from-regs, prefetch under MFMA).
// Store qk_t[b][h][t][d2] bf16, d2 = D&127.
// ---------------------------------------------------------------------------
__global__ __launch_bounds__(256, 4) void k_qk(
    const short* __restrict__ wqk_b, const short* __restrict__ xr_t,
    short* __restrict__ qk_t)
{
    __shared__ __align__(16) short As[64 * 72];   // [D-local][64 data + 8 pad]
    __shared__ __align__(16) short Bs[64 * 72];   // [t-local][64 data + 8 pad]
    int tid = threadIdx.x;
    int w = tid >> 6, lane = tid & 63;
    int quad = lane >> 4, l16 = lane & 15;
    // bijective XCD-chunked swizzle: 1024 = 8 XCDs x 128
    int bid = blockIdx.x;
    int wg = (bid & 7) * 128 + (bid >> 3);
    int Dt = wg & 15;                             // D0 = Dt*64; h = Dt>>1
    int tb = (wg >> 4) & 15;
    int b  = wg >> 8;
    int t0 = tb * 64;

    f32x4 acc[4];
    #pragma unroll
    for (int tt = 0; tt < 4; tt++) acc[tt] = (f32x4){0.f,0.f,0.f,0.f};

    int s_row = tid >> 2, s_col = (tid & 3) * 16;
    const short* Ag = wqk_b + ((size_t)Dt * 64 + s_row) * 512;
    const short* Bg = xr_t + ((size_t)b * 1024 + t0 + s_row) * 512;

    i32x4 ga[2], gb[2];
    #pragma unroll
    for (int i = 0; i < 2; i++) {
        ga[i] = *(const i32x4*)&Ag[s_col + i * 8];
        gb[i] = *(const i32x4*)&Bg[s_col + i * 8];
    }

    for (int kk = 0; kk < 512; kk += 64) {
        *(i32x4*)&As[s_row * 72 + s_col]     = ga[0];
        *(i32x4*)&As[s_row * 72 + s_col + 8] = ga[1];
        *(i32x4*)&Bs[s_row * 72 + s_col]     = gb[0];
        *(i32x4*)&Bs[s_row * 72 + s_col + 8] = gb[1];
        __syncthreads();
        if (kk < 448) {
            #pragma unroll
            for (int i = 0; i < 2; i++) {
                ga[i] = *(const i32x4*)&Ag[kk + 64 + s_col + i * 8];
                gb[i] = *(const i32x4*)&Bg[kk + 64 + s_col + i * 8];
            }
        }
        bf16x8 af[2];
        #pragma unroll
        for (int kc = 0; kc < 2; kc++)
            af[kc] = *(const bf16x8*)&As[(w * 16 + l16) * 72 + kc * 32 + quad * 8];
        __builtin_amdgcn_s_setprio(1);
        #pragma unroll
        for (int tt = 0; tt < 4; tt++) {
            bf16x8 bf0 = *(const bf16x8*)&Bs[(tt * 16 + l16) * 72 + quad * 8];
            bf16x8 bf1 = *(const bf16x8*)&Bs[(tt * 16 + l16) * 72 + 32 + quad * 8];
            acc[tt] = MFMA16(af[0], bf0, acc[tt]);
            acc[tt] = MFMA16(af[1], bf1, acc[tt]);
        }
        __builtin_amdgcn_s_setprio(0);
        __syncthreads();
    }
    int h = Dt >> 1;
    int d2 = (Dt & 1) * 64 + w * 16 + quad * 4;
    #pragma unroll
    for (int tt = 0; tt < 4; tt++) {
        bf16x4 pk;
        pk.x = f2bf(acc[tt][0]); pk.y = f2bf(acc[tt][1]);
        pk.z = f2bf(acc[tt][2]); pk.w = f2bf(acc[tt][3]);
        int t = t0 + tt * 16 + l16;
        *(bf16x4*)&qk_t[(((size_t)b * 8 + h) * 1024 + t) * 128 + d2] = pk;
    }
}

// ---------------------------------------------------------------------------
// Kernel 3: attention, NO-MAX softmax (bounded logits -> plain exp2 sums).
// mh=2 split restored: 1024 blocks (4 blocks/CU, 4 waves/SIMD co-resident),
// m-tile 64, 8 iters/block, register-double-buffered staging. 1D grid with
// XCD-chunked swizzle: the 16 nb-siblings of each (bh,mh) (shared 128KB K/V
// stream) land on one XCD's L2 (~2MB/XCD working set). Bias folded
// multiplicatively: p = exp2(s) * elut[rel]. Stores raw O + l.
// ---------------------------------------------------------------------------
__global__ __launch_bounds__(256, 4) void k_attn(
    const short* __restrict__ qk_t, const short* __restrict__ xi_v,
    const float* __restrict__ rel_bias, float* __restrict__ o_part,
    float* __restrict__ lsum)
{
    __shared__ __align__(16) short Ks[64 * 72];       // [m][64 data + 8 pad]
    __shared__ __align__(16) short Vs[64 * 72];       // [d][64 m + 8 pad]
    __shared__ __align__(16) short Ps[4][16 * 72];    // per wave [n][64 + 8 pad]
    __shared__ float elut[2048];
    int tid = threadIdx.x;
    int w = tid >> 6, lane = tid & 63;
    int quad = lane >> 4, l16 = lane & 15;
    // bijective XCD-chunked swizzle: 1024 = 8 XCDs x 128
    int bid = blockIdx.x;
    int wg = (bid & 7) * 128 + (bid >> 3);
    int nb = wg & 15;
    int mh = (wg >> 4) & 1;
    int bh = wg >> 5;
    int h = bh & 7;
    int n_base = nb * 64;

    for (int i = tid; i < 2047; i += 256) {
        int rel = i - 1023;
        int ret = (rel >= 0) ? 16 : 0;
        int na = rel < 0 ? -rel : rel;
        int idx;
        if (na < 8) idx = ret + na;
        else {
            int vl = 8 + (int)(log2f((float)na * 0.125f) * 2.0f);
            vl = vl > 15 ? 15 : vl;
            idx = ret + vl;
        }
        elut[i] = exp2f(rel_bias[idx * 8 + h] * QSCALE);
    }

    const short* qb = qk_t + (size_t)bh * (1024 * 128);
    const short* vb = xi_v + (size_t)bh * (64 * 1024);

    // Q frags (B-operand): lane holds Q[n = n_base + w*16 + l16][kk*32+quad*8+j]
    bf16x8 qf[2];
    #pragma unroll
    for (int kk = 0; kk < 2; kk++)
        qf[kk] = *(const bf16x8*)&qb[(size_t)(n_base + w * 16 + l16) * 128 + kk * 32 + quad * 8];

    f32x4 acc_o[4];
    #pragma unroll
    for (int dt = 0; dt < 4; dt++) acc_o[dt] = (f32x4){0.f,0.f,0.f,0.f};
    float l_st = 0.f;

    // staging map: 4 threads per row, 2 x 16B each
    int srow = tid >> 2;                // 0..63 (m-local for K, d for V)
    int soff = (tid & 3) * 16;          // 0,16,32,48
    int m0 = mh * 512;
    i32x4 gk[2], gv[2];
    #pragma unroll
    for (int i = 0; i < 2; i++) {
        gk[i] = *(const i32x4*)&qb[(size_t)(m0 + srow) * 128 + 64 + soff + i * 8];
        gv[i] = *(const i32x4*)&vb[(size_t)srow * 1024 + m0 + soff + i * 8];
    }

    __syncthreads();   // elut ready

    #pragma unroll 1
    for (int it = 0; it < 8; it++) {
        *(i32x4*)&Ks[srow * 72 + soff]     = gk[0];
        *(i32x4*)&Ks[srow * 72 + soff + 8] = gk[1];
        *(i32x4*)&Vs[srow * 72 + soff]     = gv[0];
        *(i32x4*)&Vs[srow * 72 + soff + 8] = gv[1];
        __syncthreads();
        // prefetch next tile into registers (overlaps compute below)
        if (it < 7) {
            int m1 = m0 + 64;
            #pragma unroll
            for (int i = 0; i < 2; i++) {
                gk[i] = *(const i32x4*)&qb[(size_t)(m1 + srow) * 128 + 64 + soff + i * 8];
                gv[i] = *(const i32x4*)&vb[(size_t)srow * 1024 + m1 + soff + i * 8];
            }
        }

        // sim^T: A = K (m rows), B = Q (n cols); D[m][n], col n = l16
        f32x4 s[4];
        __builtin_amdgcn_s_setprio(1);
        #pragma unroll
        for (int mt = 0; mt < 4; mt++) {
            bf16x8 kf0 = *(const bf16x8*)&Ks[(mt * 16 + l16) * 72 + quad * 8];
            bf16x8 kf1 = *(const bf16x8*)&Ks[(mt * 16 + l16) * 72 + 32 + quad * 8];
            f32x4 tacc = (f32x4){0.f,0.f,0.f,0.f};
            tacc = MFMA16(kf0, qf[0], tacc);
            tacc = MFMA16(kf1, qf[1], tacc);
            s[mt] = tacc;
        }
        __builtin_amdgcn_s_setprio(0);

        // p = exp2(s) * elut[rel]; accumulate l (per-lane partial)
        int n = n_base + w * 16 + l16;
        #pragma unroll
        for (int mt = 0; mt < 4; mt++) {
            int rel0 = m0 + mt * 16 + quad * 4 - n + 1023;
            #pragma unroll
            for (int j = 0; j < 4; j++) {
                float p = exp2f(s[mt][j]) * elut[rel0 + j];
                s[mt][j] = p;
                l_st += p;
            }
        }
        // pack P into per-wave LDS (C-layout -> A-layout)
        #pragma unroll
        for (int mt = 0; mt < 4; mt++) {
            bf16x4 pk;
            pk.x = f2bf(s[mt][0]); pk.y = f2bf(s[mt][1]);
            pk.z = f2bf(s[mt][2]); pk.w = f2bf(s[mt][3]);
            *(bf16x4*)&Ps[w][l16 * 72 + mt * 16 + quad * 4] = pk;
        }
        // PV: O[n][d] += P[n][m] V[m][d]
        __builtin_amdgcn_s_setprio(1);
        #pragma unroll
        for (int si = 0; si < 2; si++) {
            bf16x8 pf = *(const bf16x8*)&Ps[w][l16 * 72 + si * 32 + quad * 8];
            #pragma unroll
            for (int dt = 0; dt < 4; dt++) {
                bf16x8 vf = *(const bf16x8*)&Vs[(dt * 16 + l16) * 72 + si * 32 + quad * 8];
                acc_o[dt] = MFMA16(pf, vf, acc_o[dt]);
            }
        }
        __builtin_amdgcn_s_setprio(0);
        m0 += 64;
        __syncthreads();
    }
    // store raw O partial: o_part[mh][bh][d][n]
    #pragma unroll
    for (int dt = 0; dt < 4; dt++)
        *(f32x4*)&o_part[(((size_t)mh * 32 + bh) * 64 + dt * 16 + l16) * 1024 + n_base + w * 16 + quad * 4] = acc_o[dt];
    // store l partial (full column sum after cross-quad reduce)
    l_st += __shfl_xor(l_st, 16);
    l_st += __shfl_xor(l_st, 32);
    if (quad == 0)
        lsum[((size_t)bh * 2 + mh) * 1024 + n_base + w * 16 + l16] = l_st;
}

// ---------------------------------------------------------------------------
// Kernel 4: merge two m-halves (trivial: no max logic) + output projection
// out[b,c,f,t] = sum_h o[h] w_out[c,h]
// ---------------------------------------------------------------------------
__global__ __launch_bounds__(512) void k_proj_out(
    const float* __restrict__ o_part, const float* __restrict__ lsum,
    const float* __restrict__ w_out, float* __restrict__ out)
{
    __shared__ float w_s[512];
    __shared__ float o_s[8][64];
    int tid = threadIdx.x;
    int tx = tid & 63, ty = tid >> 6;
    int tb = blockIdx.x, f = blockIdx.y, b = blockIdx.z;
    w_s[tid] = w_out[tid];
    int t = tb * 64 + tx;
    int bh = b * 8 + ty;
    float l0 = lsum[((size_t)bh * 2 + 0) * 1024 + t];
    float l1 = lsum[((size_t)bh * 2 + 1) * 1024 + t];
    float o0 = o_part[((size_t)(0 * 32 + bh) * 64 + f) * 1024 + t];
    float o1 = o_part[((size_t)(1 * 32 + bh) * 64 + f) * 1024 + t];
    o_s[ty][tx] = (o0 + o1) / (l0 + l1);
    __syncthreads();
    float ov[8];
    #pragma unroll
    for (int hh = 0; hh < 8; hh++) ov[hh] = o_s[hh][tx];
    #pragma unroll
    for (int j = 0; j < 8; j++) {
        int c = ty * 8 + j;
        float a = 0.f;
        #pragma unroll
        for (int hh = 0; hh < 8; hh++) a = fmaf(ov[hh], w_s[c * 8 + hh], a);
        out[(((size_t)b * 64 + c) * 64 + f) * 1024 + t] = a;
    }
}

// ---------------------------------------------------------------------------
extern "C" void kernel_launch(void* const* d_in, const int* in_sizes, int n_in,
                              void* d_out, int out_size, void* d_ws, size_t ws_size,
                              hipStream_t stream)
{
    const float* x        = (const float*)d_in[0];   // [4][64][64][1024]
    const float* w_in     = (const float*)d_in[1];   // [8][64]
    const float* w_qk     = (const float*)d_in[2];   // [1024][512]
    const float* w_out    = (const float*)d_in[3];   // [64][8]
    const float* rel_bias = (const float*)d_in[4];   // [32][8]
    float* out = (float*)d_out;                      // [4][64][64][1024]

    char* ws = (char*)d_ws;                          // ~33.3 MB used
    short* wqk_b  = (short*)(ws);                    // 1 MB
    short* xi_v   = (short*)(ws + (size_t)1  * (1 << 20));  // 4 MB
    short* xr_t   = (short*)(ws + (size_t)5  * (1 << 20));  // 4 MB
    short* qk_t   = (short*)(ws + (size_t)9  * (1 << 20));  // 8 MB
    float* o_part = (float*)(ws + (size_t)17 * (1 << 20));  // 16 MB (2 halves)
    float* lsum   = (float*)(ws + (size_t)33 * (1 << 20));  // 0.25 MB

    hipLaunchKernelGGL(k_proj_in,  dim3(16, 8, 4),   dim3(256), 0, stream, x, w_in, w_qk, wqk_b, xi_v, xr_t);
    hipLaunchKernelGGL(k_qk,       dim3(1024),       dim3(256), 0, stream, wqk_b, xr_t, qk_t);
    hipLaunchKernelGGL(k_attn,     dim3(1024),       dim3(256), 0, stream, qk_t, xi_v, rel_bias, o_part, lsum);
    hipLaunchKernelGGL(k_proj_out, dim3(16, 64, 4),  dim3(512), 0, stream, o_part, lsum, w_out, out);
}